// Round 9
// baseline (175.462 us; speedup 1.0000x reference)
//
#include <hip/hip_runtime.h>
#include <math.h>

#define NN 200
#define ETOT 39800

typedef float float4v __attribute__((ext_vector_type(4)));
typedef short short8 __attribute__((ext_vector_type(8)));

__device__ __forceinline__ float sigf(float x) { return 1.0f / (1.0f + expf(-x)); }

__device__ __forceinline__ unsigned short f2b(float f) {
  unsigned u = __float_as_uint(f);
  u += 0x7fffu + ((u >> 16) & 1u);
  return (unsigned short)(u >> 16);
}
__device__ __forceinline__ float b2f16(unsigned short u) {
  return __uint_as_float(((unsigned)u) << 16);
}

// ======================= L1: prep — all raw-input-only work, coalesced =======================
// [0,256):   w1 [2048][512] -> w1T bf16 [512][2048]  (LDS transpose)
// [256,288): w2 [512][256]  -> w2T bf16 [256][512]
// [288,416): wp2 -> WrT bf16 [512][1024], WrT[j][i] = wp2[j>>2][4i+(j&3)]
// [416,672): G12[c][12] = w3 row c @ [wi|rootw|bp2]
// [672,872): P/Q per node
// [872,888): we2T bf16 [64][256]
// [888,896): gvec[512] = b3 @ Wr
// 896: wp1T   897: bcat[12] = b3 @ [wi|rootw|bp2]
__global__ __launch_bounds__(256) void k_prep(
    const float* __restrict__ w1, const float* __restrict__ w2, const float* __restrict__ wp2,
    const float* __restrict__ w3, const float* __restrict__ wi, const float* __restrict__ rootw,
    const float* __restrict__ bp2, const float* __restrict__ b3, const float* __restrict__ we2,
    const float* __restrict__ bbox, const float* __restrict__ dir,
    const float* __restrict__ we1, const float* __restrict__ be1, const float* __restrict__ wp1,
    unsigned short* __restrict__ w1T, unsigned short* __restrict__ w2T,
    unsigned short* __restrict__ WrT, unsigned short* __restrict__ we2T,
    float* __restrict__ G12f, float* __restrict__ Pm, float* __restrict__ Qm,
    float* __restrict__ gvec, float* __restrict__ wp1T, float* __restrict__ bcat) {
  __shared__ __align__(16) char sm[16640];
  const int b = blockIdx.x, tid = threadIdx.x;
  const int lane = tid & 63, wv = tid >> 6;

  if (b < 288) {
    // ---- LDS-tiled transpose f32[K][N] -> bf16[N][K] ----
    float (*lds)[65] = (float (*)[65])sm;
    const float* Wf;
    unsigned short* Wt;
    int K, N, t;
    if (b < 256) { Wf = w1; Wt = w1T; K = 2048; N = 512; t = b; }
    else { Wf = w2; Wt = w2T; K = 512; N = 256; t = b - 256; }
    const int K64 = K >> 6;
    const int kt = t % K64, nt = t / K64;
#pragma unroll 4
    for (int i = 0; i < 16; ++i) {
      int idx = tid + i * 256;
      int r = idx >> 6, c = idx & 63;
      lds[r][c] = Wf[(size_t)(kt * 64 + r) * N + nt * 64 + c];
    }
    __syncthreads();
#pragma unroll 4
    for (int i = 0; i < 16; ++i) {
      int idx = tid + i * 256;
      int r = idx >> 6, c = idx & 63;
      Wt[(size_t)(nt * 64 + r) * K + kt * 64 + c] = f2b(lds[c][r]);
    }
  } else if (b < 416) {
    // ---- WrT ----
    int k = b - 288;                         // 0..127
    int o = tid >> 6, l = tid & 63;
    const float* src = wp2 + (size_t)k * 4096;
    unsigned short* dst = WrT + (size_t)(k * 4 + o) * 1024;
    for (int i = l; i < 1024; i += 64) dst[i] = f2b(src[i * 4 + o]);
  } else if (b < 672) {
    // ---- G12 row c ----
    const int c = b - 416;
    float s[12] = {};
#pragma unroll
    for (int ii = 0; ii < 4; ++ii) {
      int i = tid + ii * 256;
      float xv = w3[(size_t)c * 1024 + i];
      float4v wi4 = ((const float4v*)wi)[i];
      float4v rw4 = ((const float4v*)rootw)[i];
      float4v bp4 = ((const float4v*)bp2)[i];
#pragma unroll
      for (int q = 0; q < 4; ++q) {
        s[q] += xv * wi4[q]; s[4 + q] += xv * rw4[q]; s[8 + q] += xv * bp4[q];
      }
    }
    float (*part)[12] = (float (*)[12])sm;
#pragma unroll
    for (int r = 0; r < 12; ++r) {
      float v = s[r];
#pragma unroll
      for (int off = 32; off > 0; off >>= 1) v += __shfl_down(v, off, 64);
      if (lane == 0) part[wv][r] = v;
    }
    __syncthreads();
    if (tid < 12) G12f[c * 12 + tid] = part[0][tid] + part[1][tid] + part[2][tid] + part[3][tid];
  } else if (b < 872) {
    // ---- P/Q ----
    const int n = b - 672, c = tid;
    float a[8];
#pragma unroll
    for (int r = 0; r < 4; ++r) a[r] = bbox[n * 4 + r] * (1.0f / 1024.0f);
#pragma unroll
    for (int r = 0; r < 4; ++r) a[4 + r] = dir[n * 4 + r];
    float p = be1[c], q = 0.0f;
#pragma unroll
    for (int r = 0; r < 8; ++r) {
      p += a[r] * we1[r * 256 + c];
      q += a[r] * we1[(8 + r) * 256 + c];
    }
    Pm[n * 256 + c] = p;
    Qm[n * 256 + c] = q;
  } else if (b < 888) {
    // ---- we2T ----
    const int f = (b - 872) * 256 + tid;
    const int c = f >> 6, k0 = (f & 63) * 4;
#pragma unroll
    for (int q = 0; q < 4; ++q)
      we2T[c * 256 + k0 + q] = f2b(we2[(k0 + q) * 64 + c]);
  } else if (b < 896) {
    // ---- gvec[j] = sum_i b3[i]*Wr[i][j] ----
    const int j = (b - 888) * 64 + (tid >> 2), p = tid & 3;
    const float* src = wp2 + (size_t)(j >> 2) * 4096 + (j & 3);
    float v = 0.f;
    for (int t = 0; t < 256; ++t) {
      int i = p + 4 * t;
      v += b3[i] * src[4 * i];
    }
    v += __shfl_down(v, 2, 4);
    v += __shfl_down(v, 1, 4);
    if (p == 0) gvec[j] = v;
  } else if (b == 896) {
    if (tid < 128) {
      float4v v = {wp1[tid], wp1[128 + tid], wp1[256 + tid], wp1[384 + tid]};
      ((float4v*)wp1T)[tid] = v;
    }
  } else {
    // ---- bcat ----
    float s[12] = {};
#pragma unroll
    for (int ii = 0; ii < 4; ++ii) {
      int i = tid + ii * 256;
      float xv = b3[i];
      float4v wi4 = ((const float4v*)wi)[i];
      float4v rw4 = ((const float4v*)rootw)[i];
      float4v bp4 = ((const float4v*)bp2)[i];
#pragma unroll
      for (int q = 0; q < 4; ++q) {
        s[q] += xv * wi4[q]; s[4 + q] += xv * rw4[q]; s[8 + q] += xv * bp4[q];
      }
    }
    float (*part)[12] = (float (*)[12])sm;
#pragma unroll
    for (int r = 0; r < 12; ++r) {
      float v = s[r];
#pragma unroll
      for (int off = 32; off > 0; off >>= 1) v += __shfl_down(v, off, 64);
      if (lane == 0) part[wv][r] = v;
    }
    __syncthreads();
    if (tid < 12) bcat[tid] = part[0][tid] + part[1][tid] + part[2][tid] + part[3][tid];
  }
}

// ======================= L2: h1 tiles (416) || G tiles (512) — all coalesced =======================
// h1 = relu(roi@w1 + b1) [208x512] bf16;  Gm[j][c] = sum_i WrT[j][i]*w3[c][i]  [512][256] bf16
__global__ __launch_bounds__(256) void k_mid(
    const float* __restrict__ roi, const unsigned short* __restrict__ w1T, const float* __restrict__ b1,
    const unsigned short* __restrict__ WrT, const float* __restrict__ w3,
    unsigned short* __restrict__ h1, unsigned short* __restrict__ Gm) {
  __shared__ float red[4][16][17];
  const int b = blockIdx.x, tid = threadIdx.x;
  const int lane = tid & 63, wv = tid >> 6, mr = lane & 15, quad = lane >> 4;

  if (b < 416) {
    // h1 tile: M=208(13) N=512(32) K=2048, A inline f32->bf16 (contiguous), B short8
    const int m0 = (b % 13) * 16, n0 = (b / 13) * 16;
    const int arow = min(m0 + mr, 199);
    const float* Ap = roi + (size_t)arow * 2048 + wv * 512 + quad * 8;
    const unsigned short* Bp = w1T + (size_t)(n0 + mr) * 2048 + wv * 512 + quad * 8;
    float4v acc = {0.f, 0.f, 0.f, 0.f};
    for (int ks = 0; ks < 16; ++ks) {
      float4v a0 = *(const float4v*)(Ap + ks * 32);
      float4v a1 = *(const float4v*)(Ap + ks * 32 + 4);
      short8 af;
      af[0]=f2b(a0[0]); af[1]=f2b(a0[1]); af[2]=f2b(a0[2]); af[3]=f2b(a0[3]);
      af[4]=f2b(a1[0]); af[5]=f2b(a1[1]); af[6]=f2b(a1[2]); af[7]=f2b(a1[3]);
      short8 bf = *(const short8*)(Bp + ks * 32);
      acc = __builtin_amdgcn_mfma_f32_16x16x32_bf16(af, bf, acc, 0, 0, 0);
    }
#pragma unroll
    for (int r = 0; r < 4; ++r) red[wv][quad * 4 + r][mr] = acc[r];
    __syncthreads();
    const int row = tid >> 4, col = tid & 15;
    float v = red[0][row][col] + red[1][row][col] + red[2][row][col] + red[3][row][col] + b1[n0 + col];
    h1[(size_t)(m0 + row) * 512 + n0 + col] = f2b(fmaxf(v, 0.f));
  } else {
    // G tile: M=512(32) over j, N=256(16) over c, K=1024; A short8 (WrT), B inline f32->bf16
    const int t = b - 416;
    const int j0 = (t % 32) * 16, c0 = (t / 32) * 16;
    const unsigned short* Ap = WrT + (size_t)(j0 + mr) * 1024 + wv * 256 + quad * 8;
    const float* Bp = w3 + (size_t)(c0 + mr) * 1024 + wv * 256 + quad * 8;
    float4v acc = {0.f, 0.f, 0.f, 0.f};
    for (int ks = 0; ks < 8; ++ks) {
      short8 af = *(const short8*)(Ap + ks * 32);
      float4v b0 = *(const float4v*)(Bp + ks * 32);
      float4v b1v = *(const float4v*)(Bp + ks * 32 + 4);
      short8 bf;
      bf[0]=f2b(b0[0]); bf[1]=f2b(b0[1]); bf[2]=f2b(b0[2]); bf[3]=f2b(b0[3]);
      bf[4]=f2b(b1v[0]); bf[5]=f2b(b1v[1]); bf[6]=f2b(b1v[2]); bf[7]=f2b(b1v[3]);
      acc = __builtin_amdgcn_mfma_f32_16x16x32_bf16(af, bf, acc, 0, 0, 0);
    }
#pragma unroll
    for (int r = 0; r < 4; ++r) red[wv][quad * 4 + r][mr] = acc[r];
    __syncthreads();
    const int row = tid >> 4, col = tid & 15;
    float v = red[0][row][col] + red[1][row][col] + red[2][row][col] + red[3][row][col];
    Gm[(size_t)(j0 + row) * 256 + c0 + col] = f2b(v);
  }
}

// ======================= L3: h2 = relu(h1 @ w2T + b2), 208 tiles =======================
__global__ __launch_bounds__(256) void k_h2(const unsigned short* __restrict__ h1,
                                            const unsigned short* __restrict__ w2T,
                                            const float* __restrict__ b2,
                                            unsigned short* __restrict__ h2) {
  __shared__ float red[4][16][17];
  const int tid = threadIdx.x, lane = tid & 63, wv = tid >> 6;
  const int m0 = (blockIdx.x % 13) * 16, n0 = (blockIdx.x / 13) * 16;
  const int mr = lane & 15, quad = lane >> 4;
  const unsigned short* Ap = h1 + (size_t)(m0 + mr) * 512 + wv * 128 + quad * 8;
  const unsigned short* Bp = w2T + (size_t)(n0 + mr) * 512 + wv * 128 + quad * 8;
  float4v acc = {0.f, 0.f, 0.f, 0.f};
#pragma unroll
  for (int s = 0; s < 4; ++s) {
    short8 af = *(const short8*)(Ap + s * 32);
    short8 bf = *(const short8*)(Bp + s * 32);
    acc = __builtin_amdgcn_mfma_f32_16x16x32_bf16(af, bf, acc, 0, 0, 0);
  }
#pragma unroll
  for (int r = 0; r < 4; ++r) red[wv][quad * 4 + r][mr] = acc[r];
  __syncthreads();
  const int row = tid >> 4, col = tid & 15;
  float v = red[0][row][col] + red[1][row][col] + red[2][row][col] + red[3][row][col] + b2[n0 + col];
  h2[(size_t)(m0 + row) * 256 + n0 + col] = f2b(fmaxf(v, 0.f));
}

// ======================= L4: Tm = h2@G + gvec (416 tiles) | nodevec (200) =======================
__global__ __launch_bounds__(256) void k_TN(const unsigned short* __restrict__ h2,
                                            const unsigned short* __restrict__ Gm,
                                            const float* __restrict__ gvec,
                                            const float* __restrict__ G12f, const float* __restrict__ bcat,
                                            const float* __restrict__ bi, const float* __restrict__ rootb,
                                            float* __restrict__ Tm, float* __restrict__ out1,
                                            float* __restrict__ Um, float* __restrict__ out0) {
  __shared__ __align__(16) char sm[4352];
  const int b = blockIdx.x, tid = threadIdx.x;
  const int lane = tid & 63, wv = tid >> 6, mr = lane & 15, quad = lane >> 4;
  if (b < 416) {
    float (*red)[16][17] = (float (*)[16][17])sm;
    const int m0 = (b % 13) * 16, n0 = (b / 13) * 16;
    const unsigned short* Ap = h2 + (size_t)(m0 + mr) * 256 + wv * 64 + quad * 8;
    const unsigned short* Bp = Gm + (size_t)(n0 + mr) * 256 + wv * 64 + quad * 8;
    float4v acc = {0.f, 0.f, 0.f, 0.f};
#pragma unroll
    for (int s = 0; s < 2; ++s) {
      short8 af = *(const short8*)(Ap + s * 32);
      short8 bf = *(const short8*)(Bp + s * 32);
      acc = __builtin_amdgcn_mfma_f32_16x16x32_bf16(af, bf, acc, 0, 0, 0);
    }
#pragma unroll
    for (int r = 0; r < 4; ++r) red[wv][quad * 4 + r][mr] = acc[r];
    __syncthreads();
    const int row = tid >> 4, col = tid & 15;
    float v = red[0][row][col] + red[1][row][col] + red[2][row][col] + red[3][row][col] + gvec[n0 + col];
    Tm[(size_t)(m0 + row) * 512 + n0 + col] = v;
  } else {
    const int n = b - 416;
    const float xv = b2f16(h2[(size_t)n * 256 + tid]);
    const float4v* g4 = (const float4v*)(G12f + tid * 12);
    float s[12];
    float4v v0 = g4[0], v1 = g4[1], v2 = g4[2];
    s[0]=xv*v0[0]; s[1]=xv*v0[1]; s[2]=xv*v0[2]; s[3]=xv*v0[3];
    s[4]=xv*v1[0]; s[5]=xv*v1[1]; s[6]=xv*v1[2]; s[7]=xv*v1[3];
    s[8]=xv*v2[0]; s[9]=xv*v2[1]; s[10]=xv*v2[2]; s[11]=xv*v2[3];
    float (*part)[12] = (float (*)[12])sm;
#pragma unroll
    for (int r = 0; r < 12; ++r) {
      float v = s[r];
#pragma unroll
      for (int off = 32; off > 0; off >>= 1) v += __shfl_down(v, off, 64);
      if (lane == 0) part[wv][r] = v;
    }
    __syncthreads();
    if (tid < 12) {
      float v = part[0][tid] + part[1][tid] + part[2][tid] + part[3][tid] + bcat[tid];
      int kind = tid >> 2, c = tid & 3;
      if (kind == 0) out1[n * 4 + c] = sigf(v + bi[c]);
      else if (kind == 1) out0[n * 4 + c] = v + rootb[c];
      else Um[n * 4 + c] = v;
    }
  }
}

// ======================= L5: fused edge kernel =======================
__global__ __launch_bounds__(256) void k_edge(
    const float* __restrict__ P, const float* __restrict__ Q,
    const unsigned short* __restrict__ we2T,
    const float* __restrict__ be2, const float* __restrict__ we3, const float* __restrict__ be3,
    const float* __restrict__ wp1T, const float* __restrict__ bp1,
    const float* __restrict__ pri,
    const float* __restrict__ T, const float* __restrict__ U,
    float* __restrict__ out0, float* __restrict__ out_ea) {
  __shared__ int src_s[64], dst_s[64];
  __shared__ float ea_s[64][4];
  __shared__ float4v wp1s[128];
  __shared__ float bp1s[128];
  __shared__ float4v Ts[2][128];
  __shared__ float Us[2][4];

  const int tid = threadIdx.x;
  const int e0 = blockIdx.x * 64;
  const int s_lo = e0 / 199;

  if (tid < 64) {
    int e = e0 + tid;
    int i = -1, j = 0;
    if (e < ETOT) {
      i = e / 199;
      int jj = e - i * 199;
      j = jj + (jj >= i ? 1 : 0);
    }
    src_s[tid] = i;
    dst_s[tid] = j;
  }
  if (tid < 128) {
    wp1s[tid] = ((const float4v*)wp1T)[tid];
    bp1s[tid] = bp1[tid];
  }
  {
    int row = tid >> 7, c = tid & 127;
    Ts[row][c] = ((const float4v*)T)[(s_lo + row) * 128 + c];
  }
  if (tid < 8) {
    int s = min(s_lo + (tid >> 2), 199);
    Us[tid >> 2][tid & 3] = U[s * 4 + (tid & 3)];
  }
  __syncthreads();

  const int lane = tid & 63;
  const int wv = tid >> 6;
  const int m = lane & 15;
  const int quad = lane >> 4;
  const int eloc = wv * 16 + m;
  const int si = src_s[eloc];
  const int dj = dst_s[eloc];

  float4v acc[4];
#pragma unroll
  for (int ct = 0; ct < 4; ++ct) { acc[ct][0] = 0.f; acc[ct][1] = 0.f; acc[ct][2] = 0.f; acc[ct][3] = 0.f; }

  const short8* W8 = (const short8*)we2T;

  for (int ks = 0; ks < 8; ++ks) {
    union { short8 s; unsigned u[4]; } af;
    af.s = (short8)0;
    if (si >= 0) {
      const float4v* p4 = (const float4v*)(P + si * 256 + ks * 32 + quad * 8);
      const float4v* q4 = (const float4v*)(Q + dj * 256 + ks * 32 + quad * 8);
      float4v v0 = p4[0] + q4[0];
      float4v v1 = p4[1] + q4[1];
      af.u[0] = (unsigned)f2b(fmaxf(v0[0], 0.f)) | ((unsigned)f2b(fmaxf(v0[1], 0.f)) << 16);
      af.u[1] = (unsigned)f2b(fmaxf(v0[2], 0.f)) | ((unsigned)f2b(fmaxf(v0[3], 0.f)) << 16);
      af.u[2] = (unsigned)f2b(fmaxf(v1[0], 0.f)) | ((unsigned)f2b(fmaxf(v1[1], 0.f)) << 16);
      af.u[3] = (unsigned)f2b(fmaxf(v1[2], 0.f)) | ((unsigned)f2b(fmaxf(v1[3], 0.f)) << 16);
    }
#pragma unroll
    for (int ct = 0; ct < 4; ++ct) {
      short8 bf = W8[(ct * 16 + m) * 32 + ks * 4 + quad];
      acc[ct] = __builtin_amdgcn_mfma_f32_16x16x32_bf16(af.s, bf, acc[ct], 0, 0, 0);
    }
  }

  float ev[4][3];
#pragma unroll
  for (int r = 0; r < 4; ++r) { ev[r][0] = 0.f; ev[r][1] = 0.f; ev[r][2] = 0.f; }
#pragma unroll
  for (int ct = 0; ct < 4; ++ct) {
    const int col = ct * 16 + m;
    const float b2v = be2[col];
    const float w0 = we3[col * 3 + 0], w1v = we3[col * 3 + 1], w2v = we3[col * 3 + 2];
#pragma unroll
    for (int r = 0; r < 4; ++r) {
      float e2 = fmaxf(acc[ct][r] + b2v, 0.f);
      ev[r][0] += e2 * w0;
      ev[r][1] += e2 * w1v;
      ev[r][2] += e2 * w2v;
    }
  }
#pragma unroll
  for (int r = 0; r < 4; ++r)
#pragma unroll
    for (int p = 0; p < 3; ++p) {
      float v = ev[r][p];
      v += __shfl_xor(v, 1, 64);
      v += __shfl_xor(v, 2, 64);
      v += __shfl_xor(v, 4, 64);
      v += __shfl_xor(v, 8, 64);
      ev[r][p] = v;
    }
  if (m == 0) {
#pragma unroll
    for (int r = 0; r < 4; ++r) {
      int el = wv * 16 + quad * 4 + r;
      int ss = src_s[el], dd = dst_s[el];
      if (ss >= 0) {
        float4v o;
        o[0] = sigf(ev[r][0] + be3[0]);
        o[1] = sigf(ev[r][1] + be3[1]);
        o[2] = sigf(ev[r][2] + be3[2]);
        o[3] = (pri[ss] > pri[dd]) ? 1.0f : 0.0f;
        *(float4v*)&ea_s[el][0] = o;
        *(float4v*)(out_ea + (size_t)(e0 + el) * 4) = o;
      }
    }
  }
  __syncthreads();

  const int ee = tid >> 2, pp = tid & 3;
  const int s2 = src_s[ee], d2 = dst_s[ee];
  float4v pm = {0.f, 0.f, 0.f, 0.f};
  if (s2 >= 0) {
    const int srow = s2 - s_lo;
    const float c0 = ea_s[ee][0], c1 = ea_s[ee][1], c2 = ea_s[ee][2], c3 = ea_s[ee][3];
#pragma unroll 8
    for (int tt = pp; tt < 128; tt += 4) {
      float4v w4 = wp1s[tt];
      float hv = bp1s[tt] + c0 * w4[0] + c1 * w4[1] + c2 * w4[2] + c3 * w4[3];
      hv = fmaxf(hv, 0.f);
      pm += hv * Ts[srow][tt];
    }
  }
#pragma unroll
  for (int o = 0; o < 4; ++o) {
    float v = pm[o];
    v += __shfl_xor(v, 1, 64);
    v += __shfl_xor(v, 2, 64);
    pm[o] = v;
  }
  if (s2 >= 0) atomicAdd(&out0[d2 * 4 + pp], Us[s2 - s_lo][pp] + pm[pp]);
}

extern "C" void kernel_launch(void* const* d_in, const int* in_sizes, int n_in,
                              void* d_out, int out_size, void* d_ws, size_t ws_size,
                              hipStream_t stream) {
  (void)in_sizes; (void)n_in; (void)out_size; (void)ws_size;
  const float* roi   = (const float*)d_in[0];
  const float* bbox  = (const float*)d_in[1];
  const float* dir   = (const float*)d_in[2];
  const float* pri   = (const float*)d_in[3];
  const float* w1    = (const float*)d_in[4];
  const float* b1    = (const float*)d_in[5];
  const float* w2    = (const float*)d_in[6];
  const float* b2    = (const float*)d_in[7];
  const float* w3    = (const float*)d_in[8];
  const float* b3    = (const float*)d_in[9];
  const float* wi    = (const float*)d_in[10];
  const float* bi    = (const float*)d_in[11];
  const float* we1   = (const float*)d_in[12];
  const float* be1   = (const float*)d_in[13];
  const float* we2   = (const float*)d_in[14];
  const float* be2   = (const float*)d_in[15];
  const float* we3   = (const float*)d_in[16];
  const float* be3   = (const float*)d_in[17];
  const float* wp1   = (const float*)d_in[18];
  const float* bp1   = (const float*)d_in[19];
  const float* wp2   = (const float*)d_in[20];
  const float* bp2   = (const float*)d_in[21];
  const float* rootw = (const float*)d_in[22];
  const float* rootb = (const float*)d_in[23];

  float* out0 = (float*)d_out;        // next_actions [200,4]
  float* out1 = out0 + 800;           // node_concepts_explicit[0] [200,4]
  float* out2 = out0 + 1600;          // edge_attributes[0] [39800,4]

  // ---- workspace ----
  unsigned short* us = (unsigned short*)d_ws;
  unsigned short* w1T  = us;                 // [512][2048] bf16
  unsigned short* w2T  = us + 1048576;       // [256][512]
  unsigned short* WrT  = us + 1179648;       // [512][1024]
  unsigned short* we2T = us + 1703936;       // [64][256]
  unsigned short* h1   = us + 1720320;       // [208][512]
  unsigned short* h2   = us + 1826816;       // [208][256]
  unsigned short* Gm   = us + 1880064;       // [512][256]
  float* fb   = (float*)(us + 2011136);
  float* Tm   = fb;                          // [208][512] f32
  float* Pm   = fb + 106496;                 // [200][256]
  float* Qm   = fb + 157696;                 // [200][256]
  float* Um   = fb + 208896;                 // [200][4]
  float* wp1T = fb + 209696;                 // float4[128]
  float* G12f = fb + 210208;                 // [256][12]
  float* gvec = fb + 213280;                 // [512]
  float* bcat = fb + 213792;                 // [12]

  k_prep<<<898, 256, 0, stream>>>(w1, w2, wp2, w3, wi, rootw, bp2, b3, we2,
                                  bbox, dir, we1, be1, wp1,
                                  w1T, w2T, WrT, we2T, G12f, Pm, Qm, gvec, wp1T, bcat);

  k_mid<<<928, 256, 0, stream>>>(roi, w1T, b1, WrT, w3, h1, Gm);

  k_h2<<<208, 256, 0, stream>>>(h1, w2T, b2, h2);

  k_TN<<<616, 256, 0, stream>>>(h2, Gm, gvec, G12f, bcat, bi, rootb, Tm, out1, Um, out0);

  k_edge<<<622, 256, 0, stream>>>(Pm, Qm, we2T, be2, we3, be3, wp1T, bp1, pri, Tm, Um, out0, out2);
}